// Round 2
// baseline (2255.399 us; speedup 1.0000x reference)
//
#include <hip/hip_runtime.h>

#define N_NODES 50000
#define N_EDGES 1600000
#define D 48
#define NODES_PER_BLOCK 32

// ---------- workspace layout (bytes) ----------
// agg     : [0, 9,600,000)           float32 [N_NODES][48]
// out_deg : [9,600,000, 9,800,000)   int32   [N_NODES]
// in_deg  : [9,800,000, 10,000,000)  int32   [N_NODES]
#define AGG_OFF     0
#define OUTDEG_OFF  9600000
#define INDEG_OFF   9800000
#define WS_ZERO_BYTES 10000000

__global__ void k_deg(const int* __restrict__ src, const int* __restrict__ dst,
                      int* __restrict__ out_deg, int* __restrict__ in_deg) {
    int i = blockIdx.x * blockDim.x + threadIdx.x;
    if (i < N_EDGES) {
        atomicAdd(&out_deg[src[i]], 1);
        atomicAdd(&in_deg[dst[i]], 1);
    }
}

// 6 threads per edge; each thread handles 8 floats (32 B) of the feature row.
__global__ void k_scatter(const int* __restrict__ src, const int* __restrict__ dst,
                          const float* __restrict__ feat,
                          const int* __restrict__ out_deg,
                          float* __restrict__ agg) {
    int i = blockIdx.x * blockDim.x + threadIdx.x;
    if (i >= N_EDGES * 6) return;
    int e = i / 6;
    int c = i - e * 6;          // chunk 0..5, 8 floats each
    int s  = src[e];
    int d0 = dst[e];
    float scale = rsqrtf(fmaxf((float)out_deg[s], 1.0f));
    const float4* fp = (const float4*)(feat + (size_t)s * D + c * 8);
    float4 v0 = fp[0];
    float4 v1 = fp[1];
    float* ap = agg + (size_t)d0 * D + c * 8;
    unsafeAtomicAdd(ap + 0, v0.x * scale);
    unsafeAtomicAdd(ap + 1, v0.y * scale);
    unsafeAtomicAdd(ap + 2, v0.z * scale);
    unsafeAtomicAdd(ap + 3, v0.w * scale);
    unsafeAtomicAdd(ap + 4, v1.x * scale);
    unsafeAtomicAdd(ap + 5, v1.y * scale);
    unsafeAtomicAdd(ap + 6, v1.z * scale);
    unsafeAtomicAdd(ap + 7, v1.w * scale);
}

// Final: h = in_deg>0 ? agg*rsqrt(in_deg) : feat ; out = relu(h @ W^T + b)
__global__ __launch_bounds__(256) void k_out(
    const float* __restrict__ agg, const int* __restrict__ in_deg,
    const float* __restrict__ feat,
    const float* __restrict__ W, const float* __restrict__ b,
    float* __restrict__ out) {
    __shared__ float Wl[D * 49];   // row od at stride 49 (bank-conflict-free)
    __shared__ float bl[D];
    __shared__ float hl[NODES_PER_BLOCK * 49];
    int tid = threadIdx.x;

    for (int i = tid; i < D * D; i += 256) {
        int od = i / D, k = i - od * D;
        Wl[od * 49 + k] = W[i];
    }
    if (tid < D) bl[tid] = b[tid];

    int node0 = blockIdx.x * NODES_PER_BLOCK;
    for (int i = tid; i < NODES_PER_BLOCK * D; i += 256) {
        int nl = i / D, k = i - nl * D;
        int n = node0 + nl;
        float h = 0.0f;
        if (n < N_NODES) {
            int indeg = in_deg[n];
            if (indeg > 0) {
                h = agg[(size_t)n * D + k] * rsqrtf((float)indeg);
            } else {
                h = feat[(size_t)n * D + k];
            }
        }
        hl[nl * 49 + k] = h;
    }
    __syncthreads();

    for (int i = tid; i < NODES_PER_BLOCK * D; i += 256) {
        int nl = i / D, od = i - nl * D;
        int n = node0 + nl;
        if (n >= N_NODES) continue;
        float acc = bl[od];
        #pragma unroll
        for (int k = 0; k < D; k++)
            acc = fmaf(hl[nl * 49 + k], Wl[od * 49 + k], acc);
        out[(size_t)n * D + od] = fmaxf(acc, 0.0f);
    }
}

extern "C" void kernel_launch(void* const* d_in, const int* in_sizes, int n_in,
                              void* d_out, int out_size, void* d_ws, size_t ws_size,
                              hipStream_t stream) {
    const float* feat = (const float*)d_in[0];
    const int*   src  = (const int*)d_in[1];
    const int*   dst  = (const int*)d_in[2];
    const float* W    = (const float*)d_in[3];
    const float* b    = (const float*)d_in[4];
    float* out = (float*)d_out;

    char* ws = (char*)d_ws;
    float* agg    = (float*)(ws + AGG_OFF);
    int*   outdeg = (int*)(ws + OUTDEG_OFF);
    int*   indeg  = (int*)(ws + INDEG_OFF);

    // zero agg + both degree arrays (ws is re-poisoned to 0xAA before every call)
    hipMemsetAsync(d_ws, 0, WS_ZERO_BYTES, stream);

    k_deg<<<(N_EDGES + 255) / 256, 256, 0, stream>>>(src, dst, outdeg, indeg);
    k_scatter<<<(N_EDGES * 6 + 255) / 256, 256, 0, stream>>>(src, dst, feat, outdeg, agg);
    k_out<<<(N_NODES + NODES_PER_BLOCK - 1) / NODES_PER_BLOCK, 256, 0, stream>>>(
        agg, indeg, feat, W, b, out);
}

// Round 3
// 413.338 us; speedup vs baseline: 5.4565x; 5.4565x over previous
//
#include <hip/hip_runtime.h>

#define N_NODES 50000
#define N_EDGES 1600000
#define D 48

// ---------- workspace layout (bytes) ----------
#define OUTDEG_OFF   0          // int[50000]
#define INDEG_OFF    200000     // int[50000]
#define RPLOCAL_OFF  400000     // int[50000]  per-block-local exclusive prefix
#define ROWPTR_OFF   600000     // int[50001]
#define ROWFILL_OFF  800064     // int[50000]  atomic cursors (init = row_ptr)
#define CI_OFF       1000064    // float[50000]
#define BSUM_OFF     1200064    // int[64]
#define BOFF_OFF     1200320    // int[64]
#define COL_OFF      1200640    // int[1600000]
#define WS_ZERO_BYTES 400000    // only the two degree histograms need zeroing

#define SCAN_T 256
#define SCAN_ELEMS 1024         // 4 elems per thread
#define NBLK 49                 // ceil(50000/1024)

__global__ void k_deg(const int* __restrict__ src, const int* __restrict__ dst,
                      int* __restrict__ out_deg, int* __restrict__ in_deg) {
    int i = blockIdx.x * blockDim.x + threadIdx.x;
    if (i < N_EDGES) {
        atomicAdd(&out_deg[src[i]], 1);
        atomicAdd(&in_deg[dst[i]], 1);
    }
}

// per-1024-chunk exclusive scan of in_deg; block totals to bsum
__global__ __launch_bounds__(SCAN_T) void k_scan1(const int* __restrict__ in_deg,
                                                  int* __restrict__ rp_local,
                                                  int* __restrict__ bsum) {
    __shared__ int ts[SCAN_T];
    int t = threadIdx.x;
    int base = blockIdx.x * SCAN_ELEMS + t * 4;
    int4 v = make_int4(0, 0, 0, 0);
    if (base < N_NODES) v = *(const int4*)(in_deg + base);   // 50000 % 4 == 0, safe
    int s0 = v.x, s01 = v.x + v.y, s012 = s01 + v.z, tot = s012 + v.w;
    ts[t] = tot;
    __syncthreads();
    for (int off = 1; off < SCAN_T; off <<= 1) {
        int x = 0;
        if (t >= off) x = ts[t - off];
        __syncthreads();
        if (t >= off) ts[t] += x;
        __syncthreads();
    }
    int incl = ts[t];
    int excl = incl - tot;
    if (base < N_NODES) {
        rp_local[base + 0] = excl;
        rp_local[base + 1] = excl + s0;
        rp_local[base + 2] = excl + s01;
        rp_local[base + 3] = excl + s012;
    }
    if (t == SCAN_T - 1) bsum[blockIdx.x] = incl;
}

// single-wave exclusive scan of the 49 block sums
__global__ void k_scan2(const int* __restrict__ bsum, int* __restrict__ boff) {
    int lane = threadIdx.x & 63;
    int v = (lane < NBLK) ? bsum[lane] : 0;
    int incl = v;
    for (int off = 1; off < 64; off <<= 1) {
        int u = __shfl_up(incl, off);
        if (lane >= off) incl += u;
    }
    if (lane < 64) boff[lane] = incl - v;
}

// row_ptr = rp_local + boff; row_fill = row_ptr; ci = rsqrt(max(out_deg,1))
__global__ void k_scan3(const int* __restrict__ rp_local, const int* __restrict__ boff,
                        const int* __restrict__ out_deg,
                        int* __restrict__ row_ptr, int* __restrict__ row_fill,
                        float* __restrict__ ci) {
    int i = blockIdx.x * blockDim.x + threadIdx.x;
    if (i < N_NODES) {
        int rp = rp_local[i] + boff[i >> 10];
        row_ptr[i] = rp;
        row_fill[i] = rp;
        ci[i] = rsqrtf(fmaxf((float)out_deg[i], 1.0f));
    }
    if (i == 0) row_ptr[N_NODES] = N_EDGES;
}

// col[pos] = src for each edge, bucketed by dst via atomic cursor
__global__ void k_fill(const int* __restrict__ src, const int* __restrict__ dst,
                       int* __restrict__ row_fill, int* __restrict__ col) {
    int e = blockIdx.x * blockDim.x + threadIdx.x;
    if (e < N_EDGES) {
        int d0 = dst[e];
        int pos = atomicAdd(&row_fill[d0], 1);
        col[pos] = src[e];
    }
}

// one wave per dst node: gather+accumulate in registers, then fused GEMM+ReLU
__global__ __launch_bounds__(256) void k_gcn(
    const int* __restrict__ row_ptr, const int* __restrict__ col,
    const float* __restrict__ ci, const float* __restrict__ feat,
    const float* __restrict__ W, const float* __restrict__ b,
    float* __restrict__ out) {
    __shared__ float Wl[D * 49];
    __shared__ float bl[D];
    __shared__ float hl[4 * 49];
    int tid = threadIdx.x;

    for (int i = tid; i < D * D; i += 256) {
        int od = i / D, k = i - od * D;
        Wl[od * 49 + k] = W[i];
    }
    if (tid < D) bl[tid] = b[tid];

    int wave = tid >> 6;
    int lane = tid & 63;
    int n = blockIdx.x * 4 + wave;
    int kk = (lane < D) ? lane : 0;     // lanes 48..63 shadow lane 0 (kept for uniform loads)

    int beg = 0, end = 0;
    if (n < N_NODES) { beg = row_ptr[n]; end = row_ptr[n + 1]; }

    float acc = 0.0f;
    int j = beg;
    for (; j + 4 <= end; j += 4) {
        int s0 = col[j], s1 = col[j + 1], s2 = col[j + 2], s3 = col[j + 3];
        float c0 = ci[s0], c1 = ci[s1], c2 = ci[s2], c3 = ci[s3];
        acc += feat[(size_t)s0 * D + kk] * c0;
        acc += feat[(size_t)s1 * D + kk] * c1;
        acc += feat[(size_t)s2 * D + kk] * c2;
        acc += feat[(size_t)s3 * D + kk] * c3;
    }
    for (; j < end; ++j) {
        int s = col[j];
        acc += feat[(size_t)s * D + kk] * ci[s];
    }

    float res = 0.0f;
    if (n < N_NODES) {
        int indeg = end - beg;
        res = (indeg > 0) ? acc * rsqrtf((float)indeg)
                          : feat[(size_t)n * D + kk];
    }
    if (lane < D) hl[wave * 49 + lane] = res;
    __syncthreads();

    if (tid < 4 * D) {
        int nl = tid / D, od = tid - nl * D;
        int n2 = blockIdx.x * 4 + nl;
        if (n2 < N_NODES) {
            float a2 = bl[od];
            #pragma unroll
            for (int k = 0; k < D; k++)
                a2 = fmaf(hl[nl * 49 + k], Wl[od * 49 + k], a2);
            out[(size_t)n2 * D + od] = fmaxf(a2, 0.0f);
        }
    }
}

extern "C" void kernel_launch(void* const* d_in, const int* in_sizes, int n_in,
                              void* d_out, int out_size, void* d_ws, size_t ws_size,
                              hipStream_t stream) {
    const float* feat = (const float*)d_in[0];
    const int*   src  = (const int*)d_in[1];
    const int*   dst  = (const int*)d_in[2];
    const float* W    = (const float*)d_in[3];
    const float* b    = (const float*)d_in[4];
    float* out = (float*)d_out;

    char* ws = (char*)d_ws;
    int*   outdeg   = (int*)(ws + OUTDEG_OFF);
    int*   indeg    = (int*)(ws + INDEG_OFF);
    int*   rp_local = (int*)(ws + RPLOCAL_OFF);
    int*   row_ptr  = (int*)(ws + ROWPTR_OFF);
    int*   row_fill = (int*)(ws + ROWFILL_OFF);
    float* ci       = (float*)(ws + CI_OFF);
    int*   bsum     = (int*)(ws + BSUM_OFF);
    int*   boff     = (int*)(ws + BOFF_OFF);
    int*   col      = (int*)(ws + COL_OFF);

    hipMemsetAsync(d_ws, 0, WS_ZERO_BYTES, stream);   // degree histograms only

    k_deg<<<(N_EDGES + 255) / 256, 256, 0, stream>>>(src, dst, outdeg, indeg);
    k_scan1<<<NBLK, SCAN_T, 0, stream>>>(indeg, rp_local, bsum);
    k_scan2<<<1, 64, 0, stream>>>(bsum, boff);
    k_scan3<<<(N_NODES + 255) / 256, 256, 0, stream>>>(rp_local, boff, outdeg,
                                                       row_ptr, row_fill, ci);
    k_fill<<<(N_EDGES + 255) / 256, 256, 0, stream>>>(src, dst, row_fill, col);
    k_gcn<<<(N_NODES + 3) / 4, 256, 0, stream>>>(row_ptr, col, ci, feat, W, b, out);
}